// Round 6
// baseline (519.695 us; speedup 1.0000x reference)
//
#include <hip/hip_runtime.h>
#include <hip/hip_bf16.h>
#include <stdint.h>

typedef __bf16 bf16x8 __attribute__((ext_vector_type(8)));
typedef float f32x4 __attribute__((ext_vector_type(4)));

#define GLB_AS __attribute__((address_space(1)))
#define LDS_AS __attribute__((address_space(3)))

__device__ __forceinline__ void gload_lds16(const void* g, void* l) {
    // dest is wave-uniform base; HW writes base + lane*16
    __builtin_amdgcn_global_load_lds((GLB_AS void*)(g), (LDS_AS void*)(l), 16, 0, 0);
}

#define GM 8192
#define GN 8192
#define GK 1024

// ---------------------------------------------------------------------------
// Kernel 1: row L2-normalize (x gets +1e-7 first), write bf16.
// ---------------------------------------------------------------------------
__global__ __launch_bounds__(256) void normalize_rows(
    const float* __restrict__ x, const float* __restrict__ ref,
    __bf16* __restrict__ outA, __bf16* __restrict__ outB)
{
    const int row = blockIdx.x;
    const bool isX = row < 8192;
    const size_t r = isX ? (size_t)row : (size_t)(row - 8192);
    const float* src = isX ? (x + r * 1024) : (ref + r * 1024);
    __bf16* dst = isX ? (outA + r * 1024) : (outB + r * 1024);
    const float eps = isX ? 1e-7f : 0.0f;

    const int t = threadIdx.x;
    float4 v = reinterpret_cast<const float4*>(src)[t];
    v.x += eps; v.y += eps; v.z += eps; v.w += eps;
    float ss = v.x * v.x + v.y * v.y + v.z * v.z + v.w * v.w;

    #pragma unroll
    for (int o = 32; o; o >>= 1) ss += __shfl_xor(ss, o, 64);

    __shared__ float red[4];
    const int wv = t >> 6, lane = t & 63;
    if (lane == 0) red[wv] = ss;
    __syncthreads();
    const float tot = red[0] + red[1] + red[2] + red[3];
    const float inv = rsqrtf(fmaxf(tot, 1e-12f));

    __bf16 b[4];
    b[0] = (__bf16)(v.x * inv);
    b[1] = (__bf16)(v.y * inv);
    b[2] = (__bf16)(v.z * inv);
    b[3] = (__bf16)(v.w * inv);
    uint2 pk;
    __builtin_memcpy(&pk, b, 8);
    reinterpret_cast<uint2*>(dst)[t] = pk;
}

// ---------------------------------------------------------------------------
// Kernel 2: PERSISTENT 256x256 8-phase bf16 GEMM (C = A . B^T) with
// SOFTWARE-PIPELINED FRAGMENT LOADS:
//   phase p: [STAGE] [(vm wait)] [MFMA p — consumes frags loaded at p-1]
//            [issue ds_reads for p+1] [(stores)] [barrier]
// so the LDS pipe (48 b128-reads/phase/CU ~575cy) overlaps the MFMA pipe
// (~620cy) instead of serializing with it. No frag double-buffering needed:
// reads issue after the MFMA cluster (register WAR is safe post-issue).
// vm accounting: vmcnt(6) steady at ph4/ph8; vmcnt(30) at store-boundary ph8
// (24 stores + 6 loads in flight). One barrier per phase (region liveness
// re-verified: every last-read -> re-stage distance >= 1 barrier).
// ---------------------------------------------------------------------------
__global__ __launch_bounds__(512, 2) void gemm_pipe(
    const __bf16* __restrict__ A, const __bf16* __restrict__ B,
    float* __restrict__ C)
{
    __shared__ __bf16 As[2][2][128][64];   // 64 KB
    __shared__ __bf16 Bs[2][2][128][64];   // 64 KB

    // block -> 2x2-tile square, XCD-clustered; snake visit order
    const int bid = blockIdx.x;
    const int xcd = bid & 7, sq = bid >> 3;          // sq 0..31
    const int u = (xcd & 3) * 4 + (sq & 3);          // 0..15
    const int v = (xcd >> 2) * 8 + (sq >> 2);        // 0..15
    const size_t u0 = (size_t)u * 512;               // A-row base of square
    const size_t v0 = (size_t)v * 512;               // B-row base of square

    const int tid  = threadIdx.x;
    const int wave = tid >> 6;
    const int lane = tid & 63;
    const int wr = wave >> 2;      // 0..1
    const int wc = wave & 3;       // 0..3

    const int srow  = lane >> 3;            // staging row within 8-row chunk
    const int sslot = (lane & 7) ^ srow;    // inverse-swizzled global k-slot
    const int fr = lane & 15;               // frag row
    const int fs = lane >> 4;               // frag k-subslot

    bf16x8 af[4][2];       // A frags for current quadrant-row
    bf16x8 bq[2][2][2];    // B frags, both qn halves held
    f32x4  acc[8][4] = {};

    // snake tile bases: tile t = q>>4; tm-off for t in {1,2}, tn-off for t>=2
#define BASE_M(q) (u0 + ((((q) >> 4) == 1 || ((q) >> 4) == 2) ? 256 : 0))
#define BASE_N(q) (v0 + ((((q) >> 4) >= 2) ? 256 : 0))

#define STAGE_A(rM, q, h, b) { \
    const size_t kcol = (size_t)((q) & 15) * 64; \
    _Pragma("unroll") \
    for (int j = 0; j < 2; ++j) { \
        const size_t grow = (rM) + (size_t)(j) * 128 + (h) * 64 + wave * 8 + srow; \
        const char* src = (const char*)A + (grow * GK + kcol) * 2 + sslot * 16; \
        char* dst = (char*)&As[b][h][0][0] + (j * 64 + wave * 8) * 128; \
        gload_lds16(src, dst); } }

#define STAGE_B(rN, q, h, b) { \
    const size_t kcol = (size_t)((q) & 15) * 64; \
    _Pragma("unroll") \
    for (int j = 0; j < 2; ++j) { \
        const int l = j * 64 + wave * 8 + srow; \
        const size_t grow = (rN) + (size_t)(l >> 5) * 64 + (h) * 32 + (l & 31); \
        const char* src = (const char*)B + (grow * GK + kcol) * 2 + sslot * 16; \
        char* dst = (char*)&Bs[b][h][0][0] + (j * 64 + wave * 8) * 128; \
        gload_lds16(src, dst); } }

#define LDA(qm, b) { \
    _Pragma("unroll") \
    for (int m = 0; m < 4; ++m) { \
        const int l = wr * 64 + m * 16 + fr; \
        _Pragma("unroll") \
        for (int ks = 0; ks < 2; ++ks) { \
            const int slot = (ks * 4 + fs) ^ (l & 7); \
            af[m][ks] = *(const bf16x8*)((const char*)&As[b][qm][0][0] + l * 128 + slot * 16); } } }

#define LDB(qn, b) { \
    _Pragma("unroll") \
    for (int n = 0; n < 2; ++n) { \
        const int l = wc * 32 + n * 16 + fr; \
        _Pragma("unroll") \
        for (int ks = 0; ks < 2; ++ks) { \
            const int slot = (ks * 4 + fs) ^ (l & 7); \
            bq[qn][n][ks] = *(const bf16x8*)((const char*)&Bs[b][qn][0][0] + l * 128 + slot * 16); } } }

// swapped operands: D = mfma(B_frag, A_frag) -> lane holds 4 consecutive C-cols
#define QMFMA(qm, qn) { \
    __builtin_amdgcn_s_setprio(1); \
    _Pragma("unroll") \
    for (int ks = 0; ks < 2; ++ks) \
    _Pragma("unroll") \
    for (int m = 0; m < 4; ++m) \
    _Pragma("unroll") \
    for (int n = 0; n < 2; ++n) \
        acc[(qm) * 4 + m][(qn) * 2 + n] = __builtin_amdgcn_mfma_f32_16x16x32_bf16( \
            bq[qn][n][ks], af[m][ks], acc[(qm) * 4 + m][(qn) * 2 + n], 0, 0, 0); \
    __builtin_amdgcn_s_setprio(0); }

// first k-step of a tile: C-in = 0 (re-inits acc without explicit zeroing)
#define QMFMA_F(qm, qn) { \
    __builtin_amdgcn_s_setprio(1); \
    _Pragma("unroll") \
    for (int m = 0; m < 4; ++m) \
    _Pragma("unroll") \
    for (int n = 0; n < 2; ++n) \
        acc[(qm) * 4 + m][(qn) * 2 + n] = __builtin_amdgcn_mfma_f32_16x16x32_bf16( \
            bq[qn][n][0], af[m][0], (f32x4){0.f, 0.f, 0.f, 0.f}, 0, 0, 0); \
    _Pragma("unroll") \
    for (int m = 0; m < 4; ++m) \
    _Pragma("unroll") \
    for (int n = 0; n < 2; ++n) \
        acc[(qm) * 4 + m][(qn) * 2 + n] = __builtin_amdgcn_mfma_f32_16x16x32_bf16( \
            bq[qn][n][1], af[m][1], acc[(qm) * 4 + m][(qn) * 2 + n], 0, 0, 0); \
    __builtin_amdgcn_s_setprio(0); }

#define MFMA_PH(isf, qm, qn) { if (isf) { QMFMA_F(qm, qn); } else { QMFMA(qm, qn); } }

// store one finalized quadrant: 8 x dwordx4, fire-and-forget
#define STORE_QUAD(qm, qn, rM, rN) { \
    _Pragma("unroll") \
    for (int m = 0; m < 4; ++m) \
    _Pragma("unroll") \
    for (int n = 0; n < 2; ++n) { \
        const size_t row = (rM) + (size_t)wr * 128 + (qm) * 64 + m * 16 + (lane & 15); \
        const size_t col = (rN) + (size_t)wc * 64 + (qn) * 32 + n * 16 + (lane >> 4) * 4; \
        *reinterpret_cast<f32x4*>(&C[row * (size_t)GN + col]) = acc[(qm) * 4 + m][(qn) * 2 + n]; } }

// sched_barrier before s_barrier: pin this phase's reads/stages above the bar
#define BARS() { __builtin_amdgcn_sched_barrier(0); __builtin_amdgcn_s_barrier(); }
#define WAIT_VM(n)   { asm volatile("s_waitcnt vmcnt(" #n ")" ::: "memory"); __builtin_amdgcn_sched_barrier(0); }

    // prologue: stage k-tiles 0,1 (minus A-h1 of k1); land k0; preload ph1 frags
    STAGE_A(u0, 0, 0, 0); STAGE_A(u0, 0, 1, 0); STAGE_B(v0, 0, 0, 0); STAGE_B(v0, 0, 1, 0);
    STAGE_A(u0, 1, 0, 1); STAGE_B(v0, 1, 0, 1); STAGE_B(v0, 1, 1, 1);
    WAIT_VM(6);
    BARS();
    LDA(0, 0); LDB(0, 0);   // fragments for ph1 (compiler inserts counted lgkm)

    #pragma unroll 1
    for (int i = 0; i < 32; ++i) {
        const int q1 = 2 * i + 1, q2 = 2 * i + 2, q3 = 2 * i + 3;
        const bool more  = (i < 31);
        const bool first = (i & 7) == 0;   // buf0 of this iter = tile's k0
        const bool lastt = (i & 7) == 7;   // buf1 of this iter = tile's k15
        const size_t rMs = u0 + (((i >> 3) == 1 || (i >> 3) == 2) ? 256 : 0);
        const size_t rNs = v0 + (((i >> 3) >= 2) ? 256 : 0);
        const size_t rM2 = BASE_M(q2), rN2 = BASE_N(q2);
        const size_t rM3 = BASE_M(q3), rN3 = BASE_N(q3);

        // ph1: MFMA Q(0,0) buf0; stage q1 A-h1; preload bq[1] (buf0)
        STAGE_A(rMs, q1, 1, 1);
        MFMA_PH(first, 0, 0);
        LDB(1, 0);
        BARS();
        // ph2: MFMA Q(0,1); stage q2 A-h0; preload af<-Q(1,*) (buf0)
        if (more) STAGE_A(rM2, q2, 0, 0);
        MFMA_PH(first, 0, 1);
        LDA(1, 0);
        BARS();
        // ph3: MFMA Q(1,0); stage q2 B-h0
        if (more) STAGE_B(rN2, q2, 0, 0);
        MFMA_PH(first, 1, 0);
        BARS();
        // ph4: stage q2 B-h1; vm-land q1; MFMA Q(1,1); preload buf1 Q(0,*)
        if (more) { STAGE_B(rN2, q2, 1, 0); WAIT_VM(6); }
        else      { WAIT_VM(0); }
        MFMA_PH(first, 1, 1);
        LDA(0, 1); LDB(0, 1);
        BARS();
        // ph5: MFMA Q(0,0) buf1; stage q2 A-h1; preload bq[1] (buf1)
        if (more) STAGE_A(rM2, q2, 1, 0);
        QMFMA(0, 0);
        LDB(1, 1);
        if (lastt) STORE_QUAD(0, 0, rMs, rNs);
        BARS();
        // ph6: MFMA Q(0,1); stage q3 A-h0; preload af<-Q(1,*) (buf1)
        if (more) STAGE_A(rM3, q3, 0, 1);
        QMFMA(0, 1);
        LDA(1, 1);
        if (lastt) STORE_QUAD(0, 1, rMs, rNs);
        BARS();
        // ph7: MFMA Q(1,0); stage q3 B-h0
        if (more) STAGE_B(rN3, q3, 0, 1);
        QMFMA(1, 0);
        if (lastt) STORE_QUAD(1, 0, rMs, rNs);
        BARS();
        // ph8: stage q3 B-h1; vm-land q2 (incl. past stores at boundary);
        //      MFMA Q(1,1); preload next iter's buf0 Q(0,*)
        if (more) {
            STAGE_B(rN3, q3, 1, 1);
            if (lastt) { WAIT_VM(30); } else { WAIT_VM(6); }
            QMFMA(1, 1);
            LDA(0, 0); LDB(0, 0);
            if (lastt) STORE_QUAD(1, 1, rMs, rNs);
            BARS();
        } else {
            QMFMA(1, 1);
            STORE_QUAD(1, 1, rMs, rNs);
        }
    }

#undef BASE_M
#undef BASE_N
#undef STAGE_A
#undef STAGE_B
#undef LDA
#undef LDB
#undef QMFMA
#undef QMFMA_F
#undef MFMA_PH
#undef STORE_QUAD
#undef BARS
#undef WAIT_VM
}

// ---------------------------------------------------------------------------
// Fallback (only if d_ws is too small): naive fp32, correct but slow.
// ---------------------------------------------------------------------------
__global__ __launch_bounds__(256) void naive_pairwise(
    const float* __restrict__ x, const float* __restrict__ ref,
    float* __restrict__ out)
{
    const int row = blockIdx.x >> 5;
    const int j = (blockIdx.x & 31) * 256 + threadIdx.x;
    const float* xr = x + (size_t)row * 1024;
    const float* rr = ref + (size_t)j * 1024;

    __shared__ float xs[1024];
    float part = 0.f;
    for (int k = threadIdx.x; k < 1024; k += 256) {
        float v = xr[k] + 1e-7f;
        xs[k] = v;
        part += v * v;
    }
    #pragma unroll
    for (int o = 32; o; o >>= 1) part += __shfl_xor(part, o, 64);
    __shared__ float red[4];
    if ((threadIdx.x & 63) == 0) red[threadIdx.x >> 6] = part;
    __syncthreads();
    const float ssx = red[0] + red[1] + red[2] + red[3];

    float ssr = 0.f, dot = 0.f;
    for (int k = 0; k < 1024; ++k) {
        float r = rr[k];
        ssr += r * r;
        dot += r * xs[k];
    }
    out[(size_t)row * 8192 + j] =
        dot * rsqrtf(fmaxf(ssx, 1e-12f)) * rsqrtf(fmaxf(ssr, 1e-12f));
}

extern "C" void kernel_launch(void* const* d_in, const int* in_sizes, int n_in,
                              void* d_out, int out_size, void* d_ws, size_t ws_size,
                              hipStream_t stream) {
    const float* x   = (const float*)d_in[0];   // [4,2048,1024] -> [8192][1024]
    const float* ref = (const float*)d_in[1];   // [8192][1024]
    float* out = (float*)d_out;                 // [8192][8192]

    const size_t need = (size_t)GM * GK * sizeof(__bf16) * 2;  // 32 MB
    if (ws_size >= need) {
        __bf16* wsA = (__bf16*)d_ws;
        __bf16* wsB = wsA + (size_t)GM * GK;
        normalize_rows<<<16384, 256, 0, stream>>>(x, ref, wsA, wsB);
        gemm_pipe<<<256, 512, 0, stream>>>(wsA, wsB, out);
    } else {
        naive_pairwise<<<8192 * 32, 256, 0, stream>>>(x, ref, out);
    }
}

// Round 7
// 193.350 us; speedup vs baseline: 2.6879x; 2.6879x over previous
//
#include <hip/hip_runtime.h>
#include <hip/hip_bf16.h>
#include <stdint.h>

typedef __bf16 bf16x8 __attribute__((ext_vector_type(8)));
typedef float f32x4 __attribute__((ext_vector_type(4)));
typedef float f32x16 __attribute__((ext_vector_type(16)));

#define GLB_AS __attribute__((address_space(1)))
#define LDS_AS __attribute__((address_space(3)))

__device__ __forceinline__ void gload_lds16(const void* g, void* l) {
    // dest is wave-uniform base; HW writes base + lane*16
    __builtin_amdgcn_global_load_lds((GLB_AS void*)(g), (LDS_AS void*)(l), 16, 0, 0);
}

#define GM 8192
#define GN 8192
#define GK 1024

// ---------------------------------------------------------------------------
// Kernel 1: row L2-normalize (x gets +1e-7 first), write bf16.
// ---------------------------------------------------------------------------
__global__ __launch_bounds__(256) void normalize_rows(
    const float* __restrict__ x, const float* __restrict__ ref,
    __bf16* __restrict__ outA, __bf16* __restrict__ outB)
{
    const int row = blockIdx.x;
    const bool isX = row < 8192;
    const size_t r = isX ? (size_t)row : (size_t)(row - 8192);
    const float* src = isX ? (x + r * 1024) : (ref + r * 1024);
    __bf16* dst = isX ? (outA + r * 1024) : (outB + r * 1024);
    const float eps = isX ? 1e-7f : 0.0f;

    const int t = threadIdx.x;
    float4 v = reinterpret_cast<const float4*>(src)[t];
    v.x += eps; v.y += eps; v.z += eps; v.w += eps;
    float ss = v.x * v.x + v.y * v.y + v.z * v.z + v.w * v.w;

    #pragma unroll
    for (int o = 32; o; o >>= 1) ss += __shfl_xor(ss, o, 64);

    __shared__ float red[4];
    const int wv = t >> 6, lane = t & 63;
    if (lane == 0) red[wv] = ss;
    __syncthreads();
    const float tot = red[0] + red[1] + red[2] + red[3];
    const float inv = rsqrtf(fmaxf(tot, 1e-12f));

    __bf16 b[4];
    b[0] = (__bf16)(v.x * inv);
    b[1] = (__bf16)(v.y * inv);
    b[2] = (__bf16)(v.z * inv);
    b[3] = (__bf16)(v.w * inv);
    uint2 pk;
    __builtin_memcpy(&pk, b, 8);
    reinterpret_cast<uint2*>(dst)[t] = pk;
}

// ---------------------------------------------------------------------------
// Kernel 2: PERSISTENT 256x256 bf16 GEMM (C = A . B^T), 4-phase iteration,
// 32x32x16 MFMA (2495 TF ceiling vs 2075 for 16x16), r5's proven
// read->lgkm(0)->consume-in-phase discipline (no cross-barrier frag liveness).
//  - 8 waves (2M x 4N), per-wave 128x64 out, acc = 8 x f32x16 (32x32 tiles)
//  - swapped operands mfma(B,A): lane holds M-row = lane&31; reg-quad = 4
//    consecutive N-cols at n = nsub*32 + qd*8 + 4*(lane>>5) -> dwordx4 stores
//  - LDS: As/Bs [2 buf][2 half][128][64], 5-bit XOR swizzle
//    slot = g ^ (r&7) ^ ((r>>3)&7), staging source slot = (lane&7)^srow^wave
//    (same involution both sides; conflict-free for 32-row b128 reads)
//  - 4 phases/iter (2 K-tiles), stages: ph1:1H ph2:2H ph3:2H ph4:3H,
//    counted vmcnt 6/8/6 at ph2/3/4 ends (lastt: 24/38; epilogue: 2/16)
// ---------------------------------------------------------------------------
__global__ __launch_bounds__(512, 2) void gemm_p4(
    const __bf16* __restrict__ A, const __bf16* __restrict__ B,
    float* __restrict__ C)
{
    __shared__ __bf16 As[2][2][128][64];   // 64 KB
    __shared__ __bf16 Bs[2][2][128][64];   // 64 KB

    // block -> 2x2-tile square, XCD-clustered; snake visit order
    const int bid = blockIdx.x;
    const int xcd = bid & 7, sq = bid >> 3;          // sq 0..31
    const int u = (xcd & 3) * 4 + (sq & 3);          // 0..15
    const int v = (xcd >> 2) * 8 + (sq >> 2);        // 0..15
    const size_t u0 = (size_t)u * 512;               // A-row base of square
    const size_t v0 = (size_t)v * 512;               // B-row base of square

    const int tid  = threadIdx.x;
    const int wave = tid >> 6;
    const int lane = tid & 63;
    const int wr = wave >> 2;      // 0..1
    const int wc = wave & 3;       // 0..3

    const int srow  = lane >> 3;                    // staging row in 8-row chunk
    const int sslot = (lane & 7) ^ srow ^ wave;     // inverse-swizzled k-slot
    const int l31 = lane & 31;
    const int hi  = lane >> 5;

    bf16x8 af[2][4];    // A frags: [m_sub_local][kk]
    bf16x8 bq[2][4];    // B frags: [n_sub][kk]
    f32x16 acc[4][2];   // [m_sub 0..3][n_sub 0..1]
    const f32x16 ZV = {};

#define BASE_M(q) (u0 + ((((q) >> 4) == 1 || ((q) >> 4) == 2) ? 256 : 0))
#define BASE_N(q) (v0 + ((((q) >> 4) >= 2) ? 256 : 0))

#define STAGE_A(rM, q, h, b) { \
    const size_t kcol = (size_t)((q) & 15) * 64; \
    _Pragma("unroll") \
    for (int j = 0; j < 2; ++j) { \
        const size_t grow = (rM) + (size_t)(j) * 128 + (h) * 64 + wave * 8 + srow; \
        const char* src = (const char*)A + (grow * GK + kcol) * 2 + sslot * 16; \
        char* dst = (char*)&As[b][h][0][0] + (j * 64 + wave * 8) * 128; \
        gload_lds16(src, dst); } }

#define STAGE_B(rN, q, h, b) { \
    const size_t kcol = (size_t)((q) & 15) * 64; \
    _Pragma("unroll") \
    for (int j = 0; j < 2; ++j) { \
        const int l = j * 64 + wave * 8 + srow; \
        const size_t grow = (rN) + (size_t)(l >> 5) * 64 + (h) * 32 + (l & 31); \
        const char* src = (const char*)B + (grow * GK + kcol) * 2 + sslot * 16; \
        char* dst = (char*)&Bs[b][h][0][0] + (j * 64 + wave * 8) * 128; \
        gload_lds16(src, dst); } }

// A frags for quadrant qm from buf b: rows wr*64 + msl*32 + l31, 4 k-steps
#define LDA32(qm, b) { \
    _Pragma("unroll") \
    for (int msl = 0; msl < 2; ++msl) { \
        const int r = wr * 64 + msl * 32 + l31; \
        const int rs = (r & 7) ^ ((r >> 3) & 7); \
        _Pragma("unroll") \
        for (int kk = 0; kk < 4; ++kk) { \
            const int slot = (kk * 2 + hi) ^ rs; \
            af[msl][kk] = *(const bf16x8*)((const char*)&As[b][qm][0][0] + r * 128 + slot * 16); } } }

// B frags (both n_subs) from buf b: row wc*32 + l31 in Bs[b][ns]
#define LDB32(b) { \
    const int rb_ = wc * 32 + l31; \
    const int rsb_ = (rb_ & 7) ^ ((rb_ >> 3) & 7); \
    _Pragma("unroll") \
    for (int ns = 0; ns < 2; ++ns) { \
        _Pragma("unroll") \
        for (int kk = 0; kk < 4; ++kk) { \
            const int slot = (kk * 2 + hi) ^ rsb_; \
            bq[ns][kk] = *(const bf16x8*)((const char*)&Bs[b][ns][0][0] + rb_ * 128 + slot * 16); } } }

// one merged phase's MFMA: quadrant-row qm (m-subs 2qm,2qm+1) x both n-subs,
// 4 k-steps of K=16. isf: zero-C on kk=0 (new tile's first K-tile).
#define MFMAQ(isf, qm) { \
    __builtin_amdgcn_s_setprio(1); \
    if (isf) { \
        _Pragma("unroll") \
        for (int msl = 0; msl < 2; ++msl) \
        _Pragma("unroll") \
        for (int ns = 0; ns < 2; ++ns) \
            acc[(qm) * 2 + msl][ns] = __builtin_amdgcn_mfma_f32_32x32x16_bf16( \
                bq[ns][0], af[msl][0], ZV, 0, 0, 0); \
    } else { \
        _Pragma("unroll") \
        for (int msl = 0; msl < 2; ++msl) \
        _Pragma("unroll") \
        for (int ns = 0; ns < 2; ++ns) \
            acc[(qm) * 2 + msl][ns] = __builtin_amdgcn_mfma_f32_32x32x16_bf16( \
                bq[ns][0], af[msl][0], acc[(qm) * 2 + msl][ns], 0, 0, 0); \
    } \
    _Pragma("unroll") \
    for (int kk = 1; kk < 4; ++kk) \
    _Pragma("unroll") \
    for (int msl = 0; msl < 2; ++msl) \
    _Pragma("unroll") \
    for (int ns = 0; ns < 2; ++ns) \
        acc[(qm) * 2 + msl][ns] = __builtin_amdgcn_mfma_f32_32x32x16_bf16( \
            bq[ns][kk], af[msl][kk], acc[(qm) * 2 + msl][ns], 0, 0, 0); \
    __builtin_amdgcn_s_setprio(0); }

// store quadrant-row qm: lane holds M-row l31; reg-quad qd = 4 consecutive
// N-cols at ns*32 + qd*8 + 4*hi  -> 16 x dwordx4
#define STORE2(qm, rM, rN) { \
    _Pragma("unroll") \
    for (int msl = 0; msl < 2; ++msl) \
    _Pragma("unroll") \
    for (int ns = 0; ns < 2; ++ns) { \
        const size_t row = (rM) + (size_t)wr * 128 + ((qm) * 2 + msl) * 32 + l31; \
        _Pragma("unroll") \
        for (int qd = 0; qd < 4; ++qd) { \
            const size_t col = (rN) + (size_t)wc * 64 + ns * 32 + qd * 8 + hi * 4; \
            f32x4 v_ = { acc[(qm) * 2 + msl][ns][qd * 4 + 0], \
                         acc[(qm) * 2 + msl][ns][qd * 4 + 1], \
                         acc[(qm) * 2 + msl][ns][qd * 4 + 2], \
                         acc[(qm) * 2 + msl][ns][qd * 4 + 3] }; \
            *reinterpret_cast<f32x4*>(&C[row * (size_t)GN + col]) = v_; } } }

#define BAR() __builtin_amdgcn_s_barrier()
#define WAIT_LGKM0() { asm volatile("s_waitcnt lgkmcnt(0)" ::: "memory"); __builtin_amdgcn_sched_barrier(0); }
#define WAIT_VM(n)   { asm volatile("s_waitcnt vmcnt(" #n ")" ::: "memory"); __builtin_amdgcn_sched_barrier(0); }

    // prologue: q0 full (8 gloads) + q1 {Ah0, Bh0, Bh1} (6 gloads)
    STAGE_A(u0, 0, 0, 0); STAGE_A(u0, 0, 1, 0); STAGE_B(v0, 0, 0, 0); STAGE_B(v0, 0, 1, 0);
    STAGE_A(u0, 1, 0, 1); STAGE_B(v0, 1, 0, 1); STAGE_B(v0, 1, 1, 1);
    WAIT_VM(6);
    BAR();

    #pragma unroll 1
    for (int i = 0; i < 32; ++i) {
        const int q1 = 2 * i + 1, q2 = 2 * i + 2, q3 = 2 * i + 3;
        const bool more  = (i < 31);
        const bool first = (i & 7) == 0;   // buf0 = tile's first K-tile
        const bool lastt = (i & 7) == 7;   // buf1 = tile's last K-tile
        const size_t rMs = u0 + (((i >> 3) == 1 || (i >> 3) == 2) ? 256 : 0);
        const size_t rNs = v0 + (((i >> 3) >= 2) ? 256 : 0);
        const size_t rM1 = BASE_M(q1);
        const size_t rM2 = BASE_M(q2), rN2 = BASE_N(q2);
        const size_t rM3 = BASE_M(q3), rN3 = BASE_N(q3);

        // ---- ph1: buf0 quadrant-row 0; stage q1 A-h1 ----
        STAGE_A(rM1, q1, 1, 1);
        LDA32(0, 0); LDB32(0);
        BAR(); WAIT_LGKM0();
        MFMAQ(first, 0);
        BAR();                       // no vm wait needed at ph1-end

        // ---- ph2: buf0 quadrant-row 1 (bq reused); stage q2 Ah0+Bh0 ----
        if (more) { STAGE_A(rM2, q2, 0, 0); STAGE_B(rN2, q2, 0, 0); }
        LDA32(1, 0);
        BAR(); WAIT_LGKM0();
        MFMAQ(first, 1);
        if (more) { WAIT_VM(6); } else { WAIT_VM(2); }
        BAR();

        // ---- ph3: buf1 quadrant-row 0; stage q2 Bh1+Ah1; stores if lastt ----
        if (more) { STAGE_B(rN2, q2, 1, 0); STAGE_A(rM2, q2, 1, 0); }
        LDA32(0, 1); LDB32(1);
        BAR(); WAIT_LGKM0();
        MFMAQ(false, 0);
        if (lastt) STORE2(0, rMs, rNs);
        if (more) {
            if (lastt) { WAIT_VM(24); } else { WAIT_VM(8); }
        } else { WAIT_VM(16); }
        BAR();

        // ---- ph4: buf1 quadrant-row 1; stage q3 Ah0+Bh0+Bh1; stores if lastt ----
        if (more) { STAGE_A(rM3, q3, 0, 1); STAGE_B(rN3, q3, 0, 1); STAGE_B(rN3, q3, 1, 1); }
        LDA32(1, 1);
        BAR(); WAIT_LGKM0();
        MFMAQ(false, 1);
        if (lastt) STORE2(1, rMs, rNs);
        if (more) {
            if (lastt) { WAIT_VM(38); } else { WAIT_VM(6); }
            BAR();
        }
        // final iter: fall through, stores drain at kernel end
    }

#undef BASE_M
#undef BASE_N
#undef STAGE_A
#undef STAGE_B
#undef LDA32
#undef LDB32
#undef MFMAQ
#undef STORE2
#undef BAR
#undef WAIT_LGKM0
#undef WAIT_VM
}

// ---------------------------------------------------------------------------
// Fallback (only if d_ws is too small): naive fp32, correct but slow.
// ---------------------------------------------------------------------------
__global__ __launch_bounds__(256) void naive_pairwise(
    const float* __restrict__ x, const float* __restrict__ ref,
    float* __restrict__ out)
{
    const int row = blockIdx.x >> 5;
    const int j = (blockIdx.x & 31) * 256 + threadIdx.x;
    const float* xr = x + (size_t)row * 1024;
    const float* rr = ref + (size_t)j * 1024;

    __shared__ float xs[1024];
    float part = 0.f;
    for (int k = threadIdx.x; k < 1024; k += 256) {
        float v = xr[k] + 1e-7f;
        xs[k] = v;
        part += v * v;
    }
    #pragma unroll
    for (int o = 32; o; o >>= 1) part += __shfl_xor(part, o, 64);
    __shared__ float red[4];
    if ((threadIdx.x & 63) == 0) red[threadIdx.x >> 6] = part;
    __syncthreads();
    const float ssx = red[0] + red[1] + red[2] + red[3];

    float ssr = 0.f, dot = 0.f;
    for (int k = 0; k < 1024; ++k) {
        float r = rr[k];
        ssr += r * r;
        dot += r * xs[k];
    }
    out[(size_t)row * 8192 + j] =
        dot * rsqrtf(fmaxf(ssx, 1e-12f)) * rsqrtf(fmaxf(ssr, 1e-12f));
}

extern "C" void kernel_launch(void* const* d_in, const int* in_sizes, int n_in,
                              void* d_out, int out_size, void* d_ws, size_t ws_size,
                              hipStream_t stream) {
    const float* x   = (const float*)d_in[0];   // [4,2048,1024] -> [8192][1024]
    const float* ref = (const float*)d_in[1];   // [8192][1024]
    float* out = (float*)d_out;                 // [8192][8192]

    const size_t need = (size_t)GM * GK * sizeof(__bf16) * 2;  // 32 MB
    if (ws_size >= need) {
        __bf16* wsA = (__bf16*)d_ws;
        __bf16* wsB = wsA + (size_t)GM * GK;
        normalize_rows<<<16384, 256, 0, stream>>>(x, ref, wsA, wsB);
        gemm_p4<<<256, 512, 0, stream>>>(wsA, wsB, out);
    } else {
        naive_pairwise<<<8192 * 32, 256, 0, stream>>>(x, ref, out);
    }
}

// Round 8
// 189.132 us; speedup vs baseline: 2.7478x; 1.0223x over previous
//
#include <hip/hip_runtime.h>
#include <hip/hip_bf16.h>
#include <stdint.h>

typedef __bf16 bf16x8 __attribute__((ext_vector_type(8)));
typedef float f32x4 __attribute__((ext_vector_type(4)));
typedef float f32x16 __attribute__((ext_vector_type(16)));

#define GLB_AS __attribute__((address_space(1)))
#define LDS_AS __attribute__((address_space(3)))

__device__ __forceinline__ void gload_lds16(const void* g, void* l) {
    // dest is wave-uniform base; HW writes base + lane*16
    __builtin_amdgcn_global_load_lds((GLB_AS void*)(g), (LDS_AS void*)(l), 16, 0, 0);
}

#define GM 8192
#define GN 8192
#define GK 1024

// ---------------------------------------------------------------------------
// Kernel 1: row L2-normalize (x gets +1e-7 first), write bf16.
// ---------------------------------------------------------------------------
__global__ __launch_bounds__(256) void normalize_rows(
    const float* __restrict__ x, const float* __restrict__ ref,
    __bf16* __restrict__ outA, __bf16* __restrict__ outB)
{
    const int row = blockIdx.x;
    const bool isX = row < 8192;
    const size_t r = isX ? (size_t)row : (size_t)(row - 8192);
    const float* src = isX ? (x + r * 1024) : (ref + r * 1024);
    __bf16* dst = isX ? (outA + r * 1024) : (outB + r * 1024);
    const float eps = isX ? 1e-7f : 0.0f;

    const int t = threadIdx.x;
    float4 v = reinterpret_cast<const float4*>(src)[t];
    v.x += eps; v.y += eps; v.z += eps; v.w += eps;
    float ss = v.x * v.x + v.y * v.y + v.z * v.z + v.w * v.w;

    #pragma unroll
    for (int o = 32; o; o >>= 1) ss += __shfl_xor(ss, o, 64);

    __shared__ float red[4];
    const int wv = t >> 6, lane = t & 63;
    if (lane == 0) red[wv] = ss;
    __syncthreads();
    const float tot = red[0] + red[1] + red[2] + red[3];
    const float inv = rsqrtf(fmaxf(tot, 1e-12f));

    __bf16 b[4];
    b[0] = (__bf16)(v.x * inv);
    b[1] = (__bf16)(v.y * inv);
    b[2] = (__bf16)(v.z * inv);
    b[3] = (__bf16)(v.w * inv);
    uint2 pk;
    __builtin_memcpy(&pk, b, 8);
    reinterpret_cast<uint2*>(dst)[t] = pk;
}

// ---------------------------------------------------------------------------
// Kernel 2: PERSISTENT 256x256 bf16 GEMM (C = A . B^T), 4 phases/iter,
// 32x32x16 MFMA, COMPILER-COUNTED lgkm overlap:
//  - no forced lgkmcnt(0): ds_reads are plain loads ordered kk-major so the
//    first 4 reads feed the first 4 MFMAs; compiler emits counted lgkmcnt
//    before each dependent MFMA -> LDS port fills later frags while early
//    MFMAs execute (read-window and MFMA-window overlap instead of summing)
//  - ONE barrier per phase, fenced by sched_barrier(0) on both sides (raw
//    s_barrier is not a scheduling fence; this pins STAGE/reads per phase)
//  - vm accounting identical to r7 (verified): steady 6/8/6, epilogue 2/16,
//    store-boundary 24/38; oldest-first drain lands each half-tile exactly
//    one phase before consumption
// ---------------------------------------------------------------------------
__global__ __launch_bounds__(512, 2) void gemm_cc(
    const __bf16* __restrict__ A, const __bf16* __restrict__ B,
    float* __restrict__ C)
{
    __shared__ __bf16 As[2][2][128][64];   // 64 KB
    __shared__ __bf16 Bs[2][2][128][64];   // 64 KB

    // block -> 2x2-tile square, XCD-clustered; snake visit order
    const int bid = blockIdx.x;
    const int xcd = bid & 7, sq = bid >> 3;          // sq 0..31
    const int u = (xcd & 3) * 4 + (sq & 3);          // 0..15
    const int v = (xcd >> 2) * 8 + (sq >> 2);        // 0..15
    const size_t u0 = (size_t)u * 512;               // A-row base of square
    const size_t v0 = (size_t)v * 512;               // B-row base of square

    const int tid  = threadIdx.x;
    const int wave = tid >> 6;
    const int lane = tid & 63;
    const int wr = wave >> 2;      // 0..1
    const int wc = wave & 3;       // 0..3

    const int srow  = lane >> 3;                    // staging row in 8-row chunk
    const int sslot = (lane & 7) ^ srow ^ wave;     // inverse-swizzled k-slot
    const int l31 = lane & 31;
    const int hi  = lane >> 5;

    bf16x8 af[2][4];    // A frags: [m_sub_local][kk]
    bf16x8 bq[2][4];    // B frags: [n_sub][kk]
    f32x16 acc[4][2];   // [m_sub 0..3][n_sub 0..1]
    const f32x16 ZV = {};

#define BASE_M(q) (u0 + ((((q) >> 4) == 1 || ((q) >> 4) == 2) ? 256 : 0))
#define BASE_N(q) (v0 + ((((q) >> 4) >= 2) ? 256 : 0))

#define STAGE_A(rM, q, h, b) { \
    const size_t kcol = (size_t)((q) & 15) * 64; \
    _Pragma("unroll") \
    for (int j = 0; j < 2; ++j) { \
        const size_t grow = (rM) + (size_t)(j) * 128 + (h) * 64 + wave * 8 + srow; \
        const char* src = (const char*)A + (grow * GK + kcol) * 2 + sslot * 16; \
        char* dst = (char*)&As[b][h][0][0] + (j * 64 + wave * 8) * 128; \
        gload_lds16(src, dst); } }

#define STAGE_B(rN, q, h, b) { \
    const size_t kcol = (size_t)((q) & 15) * 64; \
    _Pragma("unroll") \
    for (int j = 0; j < 2; ++j) { \
        const int l = j * 64 + wave * 8 + srow; \
        const size_t grow = (rN) + (size_t)(l >> 5) * 64 + (h) * 32 + (l & 31); \
        const char* src = (const char*)B + (grow * GK + kcol) * 2 + sslot * 16; \
        char* dst = (char*)&Bs[b][h][0][0] + (j * 64 + wave * 8) * 128; \
        gload_lds16(src, dst); } }

// A-row/swizzle helpers
#define AROW(msl)  (wr * 64 + (msl) * 32 + l31)
#define RSW(r)     (((r) & 7) ^ (((r) >> 3) & 7))

// load af[msl][kk] from As[b][qm]
#define LD_AF(msl, kk, qm, b) { \
    const int r_ = AROW(msl); \
    af[msl][kk] = *(const bf16x8*)((const char*)&As[b][qm][0][0] \
        + r_ * 128 + (((kk) * 2 + hi) ^ RSW(r_)) * 16); }

// load bq[ns][kk] from Bs[b][ns]
#define LD_BQ(ns, kk, b) { \
    const int r_ = wc * 32 + l31; \
    bq[ns][kk] = *(const bf16x8*)((const char*)&Bs[b][ns][0][0] \
        + r_ * 128 + (((kk) * 2 + hi) ^ RSW(r_)) * 16); }

// kk-major full load (A quadrant qm + both B subs): first 4 reads = kk 0 frags
#define LDAB_KK(qm, b) { \
    _Pragma("unroll") \
    for (int kk = 0; kk < 4; ++kk) { \
        LD_AF(0, kk, qm, b); LD_AF(1, kk, qm, b); \
        LD_BQ(0, kk, b);     LD_BQ(1, kk, b); } }

// kk-major A-only load (B frags reused from previous phase)
#define LDA_KK(qm, b) { \
    _Pragma("unroll") \
    for (int kk = 0; kk < 4; ++kk) { LD_AF(0, kk, qm, b); LD_AF(1, kk, qm, b); } }

// one phase's MFMA: quadrant-row qm x both n-subs, 4 k-steps of K=16.
#define MFMAQ(isf, qm) { \
    __builtin_amdgcn_s_setprio(1); \
    if (isf) { \
        _Pragma("unroll") \
        for (int msl = 0; msl < 2; ++msl) \
        _Pragma("unroll") \
        for (int ns = 0; ns < 2; ++ns) \
            acc[(qm) * 2 + msl][ns] = __builtin_amdgcn_mfma_f32_32x32x16_bf16( \
                bq[ns][0], af[msl][0], ZV, 0, 0, 0); \
    } else { \
        _Pragma("unroll") \
        for (int msl = 0; msl < 2; ++msl) \
        _Pragma("unroll") \
        for (int ns = 0; ns < 2; ++ns) \
            acc[(qm) * 2 + msl][ns] = __builtin_amdgcn_mfma_f32_32x32x16_bf16( \
                bq[ns][0], af[msl][0], acc[(qm) * 2 + msl][ns], 0, 0, 0); \
    } \
    _Pragma("unroll") \
    for (int kk = 1; kk < 4; ++kk) \
    _Pragma("unroll") \
    for (int msl = 0; msl < 2; ++msl) \
    _Pragma("unroll") \
    for (int ns = 0; ns < 2; ++ns) \
        acc[(qm) * 2 + msl][ns] = __builtin_amdgcn_mfma_f32_32x32x16_bf16( \
            bq[ns][kk], af[msl][kk], acc[(qm) * 2 + msl][ns], 0, 0, 0); \
    __builtin_amdgcn_s_setprio(0); }

// store quadrant-row qm: lane holds M-row l31; reg-quad qd = 4 consecutive
// N-cols at ns*32 + qd*8 + 4*hi  -> 16 x dwordx4
#define STORE2(qm, rM, rN) { \
    _Pragma("unroll") \
    for (int msl = 0; msl < 2; ++msl) \
    _Pragma("unroll") \
    for (int ns = 0; ns < 2; ++ns) { \
        const size_t row = (rM) + (size_t)wr * 128 + ((qm) * 2 + msl) * 32 + l31; \
        _Pragma("unroll") \
        for (int qd = 0; qd < 4; ++qd) { \
            const size_t col = (rN) + (size_t)wc * 64 + ns * 32 + qd * 8 + hi * 4; \
            f32x4 v_ = { acc[(qm) * 2 + msl][ns][qd * 4 + 0], \
                         acc[(qm) * 2 + msl][ns][qd * 4 + 1], \
                         acc[(qm) * 2 + msl][ns][qd * 4 + 2], \
                         acc[(qm) * 2 + msl][ns][qd * 4 + 3] }; \
            *reinterpret_cast<f32x4*>(&C[row * (size_t)GN + col]) = v_; } } }

// fenced barrier: raw s_barrier is not a memory/scheduling fence; pin both sides
#define BARX() { __builtin_amdgcn_sched_barrier(0); __builtin_amdgcn_s_barrier(); \
                 __builtin_amdgcn_sched_barrier(0); }
#define WAIT_VM(n) { asm volatile("s_waitcnt vmcnt(" #n ")" ::: "memory"); }

    // prologue: q0 full (8 gloads) + q1 {Ah0, Bh0, Bh1} (6 gloads)
    STAGE_A(u0, 0, 0, 0); STAGE_A(u0, 0, 1, 0); STAGE_B(v0, 0, 0, 0); STAGE_B(v0, 0, 1, 0);
    STAGE_A(u0, 1, 0, 1); STAGE_B(v0, 1, 0, 1); STAGE_B(v0, 1, 1, 1);
    WAIT_VM(6);
    BARX();

    #pragma unroll 1
    for (int i = 0; i < 32; ++i) {
        const int q1 = 2 * i + 1, q2 = 2 * i + 2, q3 = 2 * i + 3;
        const bool more  = (i < 31);
        const bool first = (i & 7) == 0;   // buf0 = tile's first K-tile
        const bool lastt = (i & 7) == 7;   // buf1 = tile's last K-tile
        const size_t rMs = u0 + (((i >> 3) == 1 || (i >> 3) == 2) ? 256 : 0);
        const size_t rNs = v0 + (((i >> 3) >= 2) ? 256 : 0);
        const size_t rM1 = BASE_M(q1);
        const size_t rM2 = BASE_M(q2), rN2 = BASE_N(q2);
        const size_t rM3 = BASE_M(q3), rN3 = BASE_N(q3);

        // ---- ph1: stage q1 A-h1; buf0 quadrant-row 0 ----
        STAGE_A(rM1, q1, 1, 1);
        LDAB_KK(0, 0);
        MFMAQ(first, 0);
        BARX();

        // ---- ph2: stage q2 Ah0+Bh0; buf0 quadrant-row 1 (bq reused) ----
        if (more) { STAGE_A(rM2, q2, 0, 0); STAGE_B(rN2, q2, 0, 0); }
        LDA_KK(1, 0);
        MFMAQ(first, 1);
        if (more) { WAIT_VM(6); } else { WAIT_VM(2); }
        BARX();

        // ---- ph3: stage q2 Bh1+Ah1; buf1 quadrant-row 0; stores if lastt ----
        if (more) { STAGE_B(rN2, q2, 1, 0); STAGE_A(rM2, q2, 1, 0); }
        LDAB_KK(0, 1);
        MFMAQ(false, 0);
        if (lastt) STORE2(0, rMs, rNs);
        if (more) {
            if (lastt) { WAIT_VM(24); } else { WAIT_VM(8); }
        } else { WAIT_VM(16); }
        BARX();

        // ---- ph4: stage q3 Ah0+Bh0+Bh1; buf1 quadrant-row 1; stores if lastt ----
        if (more) { STAGE_A(rM3, q3, 0, 1); STAGE_B(rN3, q3, 0, 1); STAGE_B(rN3, q3, 1, 1); }
        LDA_KK(1, 1);
        MFMAQ(false, 1);
        if (lastt) STORE2(1, rMs, rNs);
        if (more) {
            if (lastt) { WAIT_VM(38); } else { WAIT_VM(6); }
            BARX();
        }
        // final iter: fall through, stores drain at kernel end
    }

#undef BASE_M
#undef BASE_N
#undef STAGE_A
#undef STAGE_B
#undef AROW
#undef RSW
#undef LD_AF
#undef LD_BQ
#undef LDAB_KK
#undef LDA_KK
#undef MFMAQ
#undef STORE2
#undef BARX
#undef WAIT_VM
}

// ---------------------------------------------------------------------------
// Fallback (only if d_ws is too small): naive fp32, correct but slow.
// ---------------------------------------------------------------------------
__global__ __launch_bounds__(256) void naive_pairwise(
    const float* __restrict__ x, const float* __restrict__ ref,
    float* __restrict__ out)
{
    const int row = blockIdx.x >> 5;
    const int j = (blockIdx.x & 31) * 256 + threadIdx.x;
    const float* xr = x + (size_t)row * 1024;
    const float* rr = ref + (size_t)j * 1024;

    __shared__ float xs[1024];
    float part = 0.f;
    for (int k = threadIdx.x; k < 1024; k += 256) {
        float v = xr[k] + 1e-7f;
        xs[k] = v;
        part += v * v;
    }
    #pragma unroll
    for (int o = 32; o; o >>= 1) part += __shfl_xor(part, o, 64);
    __shared__ float red[4];
    if ((threadIdx.x & 63) == 0) red[threadIdx.x >> 6] = part;
    __syncthreads();
    const float ssx = red[0] + red[1] + red[2] + red[3];

    float ssr = 0.f, dot = 0.f;
    for (int k = 0; k < 1024; ++k) {
        float r = rr[k];
        ssr += r * r;
        dot += r * xs[k];
    }
    out[(size_t)row * 8192 + j] =
        dot * rsqrtf(fmaxf(ssx, 1e-12f)) * rsqrtf(fmaxf(ssr, 1e-12f));
}

extern "C" void kernel_launch(void* const* d_in, const int* in_sizes, int n_in,
                              void* d_out, int out_size, void* d_ws, size_t ws_size,
                              hipStream_t stream) {
    const float* x   = (const float*)d_in[0];   // [4,2048,1024] -> [8192][1024]
    const float* ref = (const float*)d_in[1];   // [8192][1024]
    float* out = (float*)d_out;                 // [8192][8192]

    const size_t need = (size_t)GM * GK * sizeof(__bf16) * 2;  // 32 MB
    if (ws_size >= need) {
        __bf16* wsA = (__bf16*)d_ws;
        __bf16* wsB = wsA + (size_t)GM * GK;
        normalize_rows<<<16384, 256, 0, stream>>>(x, ref, wsA, wsB);
        gemm_cc<<<256, 512, 0, stream>>>(wsA, wsB, out);
    } else {
        naive_pairwise<<<8192 * 32, 256, 0, stream>>>(x, ref, out);
    }
}

// Round 9
// 185.910 us; speedup vs baseline: 2.7954x; 1.0173x over previous
//
#include <hip/hip_runtime.h>
#include <hip/hip_bf16.h>
#include <stdint.h>

typedef __bf16 bf16x8 __attribute__((ext_vector_type(8)));
typedef float f32x4 __attribute__((ext_vector_type(4)));

#define GLB_AS __attribute__((address_space(1)))
#define LDS_AS __attribute__((address_space(3)))

__device__ __forceinline__ void gload_lds16(const void* g, void* l) {
    // dest is wave-uniform base; HW writes base + lane*16
    __builtin_amdgcn_global_load_lds((GLB_AS void*)(g), (LDS_AS void*)(l), 16, 0, 0);
}

#define GM 8192
#define GN 8192
#define GK 1024
#define NT (GK / 64)   // 16 K-tiles of 64
#define NI (NT / 2)    // 8 iterations, 2 K-tiles each

// ---------------------------------------------------------------------------
// Kernel 1: row L2-normalize (x gets +1e-7 first), write bf16.
// ---------------------------------------------------------------------------
__global__ __launch_bounds__(256) void normalize_rows(
    const float* __restrict__ x, const float* __restrict__ ref,
    __bf16* __restrict__ outA, __bf16* __restrict__ outB)
{
    const int row = blockIdx.x;
    const bool isX = row < 8192;
    const size_t r = isX ? (size_t)row : (size_t)(row - 8192);
    const float* src = isX ? (x + r * 1024) : (ref + r * 1024);
    __bf16* dst = isX ? (outA + r * 1024) : (outB + r * 1024);
    const float eps = isX ? 1e-7f : 0.0f;

    const int t = threadIdx.x;
    float4 v = reinterpret_cast<const float4*>(src)[t];
    v.x += eps; v.y += eps; v.z += eps; v.w += eps;
    float ss = v.x * v.x + v.y * v.y + v.z * v.z + v.w * v.w;

    #pragma unroll
    for (int o = 32; o; o >>= 1) ss += __shfl_xor(ss, o, 64);

    __shared__ float red[4];
    const int wv = t >> 6, lane = t & 63;
    if (lane == 0) red[wv] = ss;
    __syncthreads();
    const float tot = red[0] + red[1] + red[2] + red[3];
    const float inv = rsqrtf(fmaxf(tot, 1e-12f));

    __bf16 b[4];
    b[0] = (__bf16)(v.x * inv);
    b[1] = (__bf16)(v.y * inv);
    b[2] = (__bf16)(v.z * inv);
    b[3] = (__bf16)(v.w * inv);
    uint2 pk;
    __builtin_memcpy(&pk, b, 8);
    reinterpret_cast<uint2*>(dst)[t] = pk;
}

// ---------------------------------------------------------------------------
// Kernel 2: 256x256 8-phase bf16 GEMM (C = A . B^T) — LITERAL m201 template:
//  - per phase: [plain ds_reads] [stage half-tile] [lgkmcnt(8) if 12 reads]
//               [raw s_barrier] [bare lgkmcnt(0)] [setprio1 16xMFMA setprio0]
//               [raw s_barrier]
//  - NO sched_barrier anywhere; "memory" clobber ONLY on vm-waits (protects
//    ds_read-vs-DMA ordering; register-only MFMAs remain free to schedule,
//    which is what lets the compiler interleave reads with the MFMA cluster)
//  - vmcnt(6) only at phases 4 and 8 (3 half-tiles in flight)
//  - all 12 per-lane LDS read byte-offsets precomputed (zero per-phase VALU)
//  - swapped-operand MFMA + row-major dwordx4 epilogue stores (verified r3+)
// ---------------------------------------------------------------------------
__global__ __launch_bounds__(512, 2) void gemm_v9(
    const __bf16* __restrict__ A, const __bf16* __restrict__ B,
    float* __restrict__ C)
{
    __shared__ __bf16 As[2][2][128][64];   // 64 KB
    __shared__ __bf16 Bs[2][2][128][64];   // 64 KB

    // XCD-bijective swizzle (1024 % 8 == 0), then 4x4 supertile for L2
    const int bid = blockIdx.x;
    const int swz = (bid & 7) * 128 + (bid >> 3);
    const int within = swz & 15;
    const int super  = swz >> 4;
    const int tm = (super & 7) * 4 + (within & 3);
    const int tn = (super >> 3) * 4 + (within >> 2);
    const size_t rowM0 = (size_t)tm * 256;
    const size_t rowN0 = (size_t)tn * 256;

    const int tid  = threadIdx.x;
    const int wave = tid >> 6;
    const int lane = tid & 63;
    const int wr = wave >> 2;      // 0..1
    const int wc = wave & 3;       // 0..3

    const int srow  = lane >> 3;            // staging: row within 8-row chunk
    const int sslot = (lane & 7) ^ srow;    // inverse-swizzled global k-slot
    const int fr = lane & 15;               // frag row
    const int fs = lane >> 4;               // frag k-subslot

    // precomputed loop-invariant LDS read byte-offsets
    int woffA[4][2], woffB[2][2];
    #pragma unroll
    for (int m = 0; m < 4; ++m) {
        const int l = wr * 64 + m * 16 + fr;
        #pragma unroll
        for (int ks = 0; ks < 2; ++ks)
            woffA[m][ks] = l * 128 + (((ks * 4 + fs) ^ (l & 7)) * 16);
    }
    #pragma unroll
    for (int n = 0; n < 2; ++n) {
        const int l = wc * 32 + n * 16 + fr;
        #pragma unroll
        for (int ks = 0; ks < 2; ++ks)
            woffB[n][ks] = l * 128 + (((ks * 4 + fs) ^ (l & 7)) * 16);
    }

    bf16x8 af[4][2];       // A frags: current qm, [m_local][ks]
    bf16x8 bq[2][2][2];    // B frags: both qn held, [qn][n_local][ks]
    f32x4  acc[8][4] = {};

#define STAGE_A(T, h, b) { \
    _Pragma("unroll") \
    for (int j = 0; j < 2; ++j) { \
        const size_t grow = rowM0 + (size_t)(j) * 128 + (h) * 64 + wave * 8 + srow; \
        const char* src = (const char*)A + (grow * GK + (size_t)(T) * 64) * 2 + sslot * 16; \
        char* dst = (char*)&As[b][h][0][0] + (j * 64 + wave * 8) * 128; \
        gload_lds16(src, dst); } }

#define STAGE_B(T, h, b) { \
    _Pragma("unroll") \
    for (int j = 0; j < 2; ++j) { \
        const int l = j * 64 + wave * 8 + srow; \
        const size_t grow = rowN0 + (size_t)(l >> 5) * 64 + (h) * 32 + (l & 31); \
        const char* src = (const char*)B + (grow * GK + (size_t)(T) * 64) * 2 + sslot * 16; \
        char* dst = (char*)&Bs[b][h][0][0] + (j * 64 + wave * 8) * 128; \
        gload_lds16(src, dst); } }

#define LDA(qm, b) { \
    _Pragma("unroll") \
    for (int m = 0; m < 4; ++m) \
    _Pragma("unroll") \
    for (int ks = 0; ks < 2; ++ks) \
        af[m][ks] = *(const bf16x8*)((const char*)&As[b][qm][0][0] + woffA[m][ks]); }

#define LDB(qn, b) { \
    _Pragma("unroll") \
    for (int n = 0; n < 2; ++n) \
    _Pragma("unroll") \
    for (int ks = 0; ks < 2; ++ks) \
        bq[qn][n][ks] = *(const bf16x8*)((const char*)&Bs[b][qn][0][0] + woffB[n][ks]); }

// swapped operands: D = mfma(B_frag, A_frag) -> lane holds one C-row's
// 4 consecutive cols per reg quad
#define QMFMA(qm, qn) { \
    __builtin_amdgcn_s_setprio(1); \
    _Pragma("unroll") \
    for (int ks = 0; ks < 2; ++ks) \
    _Pragma("unroll") \
    for (int m = 0; m < 4; ++m) \
    _Pragma("unroll") \
    for (int n = 0; n < 2; ++n) \
        acc[(qm) * 4 + m][(qn) * 2 + n] = __builtin_amdgcn_mfma_f32_16x16x32_bf16( \
            bq[qn][n][ks], af[m][ks], acc[(qm) * 4 + m][(qn) * 2 + n], 0, 0, 0); \
    __builtin_amdgcn_s_setprio(0); }

#define STORE_QUAD(qm, qn) { \
    _Pragma("unroll") \
    for (int m = 0; m < 4; ++m) \
    _Pragma("unroll") \
    for (int n = 0; n < 2; ++n) { \
        const size_t row = rowM0 + (size_t)wr * 128 + (qm) * 64 + m * 16 + (lane & 15); \
        const size_t col = rowN0 + (size_t)wc * 64 + (qn) * 32 + n * 16 + (lane >> 4) * 4; \
        *reinterpret_cast<f32x4*>(&C[row * (size_t)GN + col]) = acc[(qm) * 4 + m][(qn) * 2 + n]; } }

#define BAR() __builtin_amdgcn_s_barrier()
#define LGKM8()  asm volatile("s_waitcnt lgkmcnt(8)")
#define LGKM0()  asm volatile("s_waitcnt lgkmcnt(0)")
#define VM(n)    asm volatile("s_waitcnt vmcnt(" #n ")" ::: "memory")

    // prologue: tile0 fully, tile1 minus A-h1 (staged at phase 1)
    STAGE_A(0, 0, 0); STAGE_A(0, 1, 0); STAGE_B(0, 0, 0); STAGE_B(0, 1, 0);
    STAGE_A(1, 0, 1); STAGE_B(1, 0, 1); STAGE_B(1, 1, 1);
    VM(6);
    BAR();

    #pragma unroll 1
    for (int i = 0; i < NI; ++i) {
        const int t1 = 2 * i + 1, t2 = 2 * i + 2, t3 = 2 * i + 3;
        const bool more = (i < NI - 1);

        // phase 1: Q(0,0) of tile t0 (buf0); stage t1 A-h1
        LDA(0, 0); LDB(0, 0);
        STAGE_A(t1, 1, 1);
        LGKM8();
        BAR(); LGKM0();
        QMFMA(0, 0);
        BAR();
        // phase 2: Q(0,1); stage t2 A-h0
        LDB(1, 0);
        if (more) STAGE_A(t2, 0, 0);
        BAR(); LGKM0();
        QMFMA(0, 1);
        BAR();
        // phase 3: Q(1,0); stage t2 B-h0
        LDA(1, 0);
        if (more) STAGE_B(t2, 0, 0);
        BAR(); LGKM0();
        QMFMA(1, 0);
        BAR();
        // phase 4: Q(1,1); stage t2 B-h1; counted vmcnt covers tile t1
        if (more) { STAGE_B(t2, 1, 0); VM(6); }
        else      { VM(0); }
        BAR();
        QMFMA(1, 1);
        BAR();
        // phase 5: Q(0,0) of tile t1 (buf1); stage t2 A-h1
        LDA(0, 1); LDB(0, 1);
        if (more) STAGE_A(t2, 1, 0);
        LGKM8();
        BAR(); LGKM0();
        QMFMA(0, 0);
        BAR();
        // phase 6: Q(0,1); stage t3 A-h0
        LDB(1, 1);
        if (more) STAGE_A(t3, 0, 1);
        BAR(); LGKM0();
        QMFMA(0, 1);
        BAR();
        // phase 7: Q(1,0); stage t3 B-h0
        LDA(1, 1);
        if (more) STAGE_B(t3, 0, 1);
        BAR(); LGKM0();
        QMFMA(1, 0);
        BAR();
        // phase 8: Q(1,1); stage t3 B-h1; counted vmcnt covers tile t2
        if (more) {
            STAGE_B(t3, 1, 1); VM(6);
            BAR();
            QMFMA(1, 1);
            BAR();
        } else {
            QMFMA(1, 1);
        }
    }

    // epilogue: stores drain at kernel end
    STORE_QUAD(0, 0); STORE_QUAD(0, 1); STORE_QUAD(1, 0); STORE_QUAD(1, 1);

#undef STAGE_A
#undef STAGE_B
#undef LDA
#undef LDB
#undef QMFMA
#undef STORE_QUAD
#undef BAR
#undef LGKM8
#undef LGKM0
#undef VM
}

// ---------------------------------------------------------------------------
// Fallback (only if d_ws is too small): naive fp32, correct but slow.
// ---------------------------------------------------------------------------
__global__ __launch_bounds__(256) void naive_pairwise(
    const float* __restrict__ x, const float* __restrict__ ref,
    float* __restrict__ out)
{
    const int row = blockIdx.x >> 5;
    const int j = (blockIdx.x & 31) * 256 + threadIdx.x;
    const float* xr = x + (size_t)row * 1024;
    const float* rr = ref + (size_t)j * 1024;

    __shared__ float xs[1024];
    float part = 0.f;
    for (int k = threadIdx.x; k < 1024; k += 256) {
        float v = xr[k] + 1e-7f;
        xs[k] = v;
        part += v * v;
    }
    #pragma unroll
    for (int o = 32; o; o >>= 1) part += __shfl_xor(part, o, 64);
    __shared__ float red[4];
    if ((threadIdx.x & 63) == 0) red[threadIdx.x >> 6] = part;
    __syncthreads();
    const float ssx = red[0] + red[1] + red[2] + red[3];

    float ssr = 0.f, dot = 0.f;
    for (int k = 0; k < 1024; ++k) {
        float r = rr[k];
        ssr += r * r;
        dot += r * xs[k];
    }
    out[(size_t)row * 8192 + j] =
        dot * rsqrtf(fmaxf(ssx, 1e-12f)) * rsqrtf(fmaxf(ssr, 1e-12f));
}

extern "C" void kernel_launch(void* const* d_in, const int* in_sizes, int n_in,
                              void* d_out, int out_size, void* d_ws, size_t ws_size,
                              hipStream_t stream) {
    const float* x   = (const float*)d_in[0];   // [4,2048,1024] -> [8192][1024]
    const float* ref = (const float*)d_in[1];   // [8192][1024]
    float* out = (float*)d_out;                 // [8192][8192]

    const size_t need = (size_t)GM * GK * sizeof(__bf16) * 2;  // 32 MB
    if (ws_size >= need) {
        __bf16* wsA = (__bf16*)d_ws;
        __bf16* wsB = wsA + (size_t)GM * GK;
        normalize_rows<<<16384, 256, 0, stream>>>(x, ref, wsA, wsB);
        gemm_v9<<<(GM / 256) * (GN / 256), 512, 0, stream>>>(wsA, wsB, out);
    } else {
        naive_pairwise<<<8192 * 32, 256, 0, stream>>>(x, ref, out);
    }
}